// Round 5
// baseline (96.906 us; speedup 1.0000x reference)
//
#include <hip/hip_runtime.h>
#include <hip/hip_bf16.h>

// FilterBank via bf16 MFMA, swapped operands:
//   D[t_row, band_col] = sum_k A[t,k] B[k,band],  A[i,k] = xpad[tb+i+k+2],
//   B[k,n] = W[n,k]  (xpad[i] = x[i-64], zero outside [0,1000))
// MFMA 16x16x32 bf16. C/D layout: col = lane&15 = band, row = 4*(lane>>4)+reg
// = t-offset -> each lane's 4 acc regs are 4 CONSECUTIVE t for one band ->
// direct float4 store, NO LDS transpose, no staging buffer.
// A-frag window slides 16 t per tile: frag(tile m, kk) = F[m + 2kk] ->
// 8-slot ring, 1 new ds_read_b128 per tile. 8 shifted bf16 LDS copies make
// every window read 16B-aligned (alignment class (i+2)&7 is per-lane const).
// Taps fused (B-frags built from global kern, 4.5KB L1-resident).

#define T_LEN    1000
#define NB       9
#define S_COPY   1160      // elements per shifted copy (multiple of 8)
#define SLOTS    145       // 16B slots (8 elems) per copy

typedef __attribute__((ext_vector_type(8))) short short8;
typedef __attribute__((ext_vector_type(4))) float f32x4;

__device__ __forceinline__ unsigned int f2bf(float f) {
    union { __hip_bfloat16 h; unsigned short u; } cv;
    cv.h = __float2bfloat16(f);
    return (unsigned int)cv.u;
}

__global__ __launch_bounds__(256, 5) void fbank_mfma(
    const float* __restrict__ x,
    const float* __restrict__ kern,
    float* __restrict__ out)
{
    __shared__ unsigned short xs[8 * S_COPY];    // 18560 B

    const int tid = threadIdx.x;
    const int bc  = blockIdx.x;                  // b*64 + c
    const int b   = bc >> 6, c = bc & 63;
    const float* xrow = x + (size_t)bc * T_LEN;

    // ---- stage 8 shifted bf16 copies: copy r, slot q = xpad[8q+r .. +7] ----
    {
        const int r = tid >> 5, q0 = tid & 31;
        #pragma unroll
        for (int i = 0; i < 5; ++i) {
            int q = q0 + 32 * i;
            if (q < SLOTS) {
                int idx0 = 8 * q + r - 64;       // x-index of element 0
                unsigned int d[4];
                #pragma unroll
                for (int e2 = 0; e2 < 4; ++e2) {
                    int i0 = idx0 + 2 * e2, i1 = i0 + 1;
                    float v0 = ((unsigned)i0 < T_LEN) ? xrow[i0] : 0.f;
                    float v1 = ((unsigned)i1 < T_LEN) ? xrow[i1] : 0.f;
                    d[e2] = f2bf(v0) | (f2bf(v1) << 16);
                }
                *reinterpret_cast<uint4*>(&xs[r * S_COPY + 8 * q]) =
                    make_uint4(d[0], d[1], d[2], d[3]);
            }
        }
    }

    const int lane = tid & 63;
    const int wid  = tid >> 6;
    const int n = lane & 15, g = lane >> 4;      // n = band col, g = k/row group

    // ---- B frags (taps) from global kern, loop-invariant ----
    short8 bt[4];
    #pragma unroll
    for (int kk = 0; kk < 4; ++kk) {
        unsigned int u[4];
        #pragma unroll
        for (int e2 = 0; e2 < 4; ++e2) {
            int k0 = kk * 32 + 8 * g + 2 * e2;
            float v0 = (n < NB && k0 < 125)     ? kern[n * 125 + k0]     : 0.f;
            float v1 = (n < NB && k0 + 1 < 125) ? kern[n * 125 + k0 + 1] : 0.f;
            u[e2] = f2bf(v0) | (f2bf(v1) << 16);
        }
        union { uint4 u4; short8 s8; } cv;
        cv.u4 = make_uint4(u[0], u[1], u[2], u[3]);
        bt[kk] = cv.s8;
    }

    __syncthreads();

    const int t0w = wid << 8;                    // wave owns t in [256w, 256w+256)
    const int rl  = (n + 2) & 7;                 // A-row i = n : alignment class
    const char* xsb = reinterpret_cast<const char*>(xs);
    // F[u] element index s = t0w + 2 + n + 8g + 16u, LDS elem = 1159*rl + s
    const int LB = 2 * (1159 * rl + 2 + n + 8 * g + t0w);

    short8 F[8];
    #pragma unroll
    for (int u = 0; u < 6; ++u)
        F[u] = *reinterpret_cast<const short8*>(xsb + LB + 32 * u);

    const bool bandok = (n < NB);
    float* obase = out + ((size_t)(b * NB + n) * 64 + c) * T_LEN + t0w + 4 * g;

    #pragma unroll
    for (int m = 0; m < 16; ++m) {               // 16-t tile per iter
        F[(m + 6) & 7] = *reinterpret_cast<const short8*>(xsb + LB + 32 * (m + 6));
        f32x4 acc = {0.f, 0.f, 0.f, 0.f};
        #pragma unroll
        for (int kk = 0; kk < 4; ++kk)
            acc = __builtin_amdgcn_mfma_f32_16x16x32_bf16(F[(m + 2 * kk) & 7], bt[kk], acc, 0, 0, 0);
        const int t4 = t0w + 16 * m + 4 * g;
        if (bandok && t4 + 4 <= T_LEN)
            __builtin_nontemporal_store(acc, reinterpret_cast<f32x4*>(obase + 16 * m));
    }
}

extern "C" void kernel_launch(void* const* d_in, const int* in_sizes, int n_in,
                              void* d_out, int out_size, void* d_ws, size_t ws_size,
                              hipStream_t stream) {
    const float* x    = (const float*)d_in[0];
    const float* kern = (const float*)d_in[1];
    float* out = (float*)d_out;

    fbank_mfma<<<64 * 64, 256, 0, stream>>>(x, kern, out);
}

// Round 6
// 60.286 us; speedup vs baseline: 1.6074x; 1.6074x over previous
//
#include <hip/hip_runtime.h>
#include <hip/hip_bf16.h>

// FilterBank via bf16 MFMA, swapped operands:
//   D[t_row, band_col] = sum_k A[t,k] B[k,band],  A[i,k] = xpad[tb+i+k+2],
//   B[k,n] = W[n,k]  (xpad[i] = x[i-64], zero outside [0,1000))
// MFMA 16x16x32 bf16. C/D layout: col = lane&15 = band, row = 4*(lane>>4)+reg
// = t-offset -> each lane's 4 acc regs are 4 CONSECUTIVE t for one band ->
// direct float4 store, NO LDS transpose, no staging buffer.
// A-frag window slides 16 t per tile: frag(tile m, kk) = F[m + 2kk] ->
// 8-slot ring, 1 new ds_read_b128 per tile. 8 shifted bf16 LDS copies make
// every window read 16B-aligned (alignment class (i+2)&7 is per-lane const).
// Round 6: NORMAL cached stores (round 5's nontemporal hint streamed 64B
// half-lines out of L2 before the sibling tile could merge -> WRITE_SIZE
// 144->230 MB, 2x slowdown). Tiles m, m+1 fill each 128B line back-to-back;
// L2 merges and writes full lines.

#define T_LEN    1000
#define NB       9
#define S_COPY   1160      // elements per shifted copy (multiple of 8)
#define SLOTS    145       // 16B slots (8 elems) per copy

typedef __attribute__((ext_vector_type(8))) short short8;
typedef __attribute__((ext_vector_type(4))) float f32x4;

__device__ __forceinline__ unsigned int f2bf(float f) {
    union { __hip_bfloat16 h; unsigned short u; } cv;
    cv.h = __float2bfloat16(f);
    return (unsigned int)cv.u;
}

__global__ __launch_bounds__(256) void fbank_mfma(
    const float* __restrict__ x,
    const float* __restrict__ kern,
    float* __restrict__ out)
{
    __shared__ unsigned short xs[8 * S_COPY];    // 18560 B

    const int tid = threadIdx.x;
    const int bc  = blockIdx.x;                  // b*64 + c
    const int b   = bc >> 6, c = bc & 63;
    const float* xrow = x + (size_t)bc * T_LEN;

    // ---- stage 8 shifted bf16 copies: copy r, slot q = xpad[8q+r .. +7] ----
    {
        const int r = tid >> 5, q0 = tid & 31;
        #pragma unroll
        for (int i = 0; i < 5; ++i) {
            int q = q0 + 32 * i;
            if (q < SLOTS) {
                int idx0 = 8 * q + r - 64;       // x-index of element 0
                unsigned int d[4];
                #pragma unroll
                for (int e2 = 0; e2 < 4; ++e2) {
                    int i0 = idx0 + 2 * e2, i1 = i0 + 1;
                    float v0 = ((unsigned)i0 < T_LEN) ? xrow[i0] : 0.f;
                    float v1 = ((unsigned)i1 < T_LEN) ? xrow[i1] : 0.f;
                    d[e2] = f2bf(v0) | (f2bf(v1) << 16);
                }
                *reinterpret_cast<uint4*>(&xs[r * S_COPY + 8 * q]) =
                    make_uint4(d[0], d[1], d[2], d[3]);
            }
        }
    }

    const int lane = tid & 63;
    const int wid  = tid >> 6;
    const int n = lane & 15, g = lane >> 4;      // n = band col, g = k/row group

    // ---- B frags (taps) from global kern, loop-invariant ----
    short8 bt[4];
    #pragma unroll
    for (int kk = 0; kk < 4; ++kk) {
        unsigned int u[4];
        #pragma unroll
        for (int e2 = 0; e2 < 4; ++e2) {
            int k0 = kk * 32 + 8 * g + 2 * e2;
            float v0 = (n < NB && k0 < 125)     ? kern[n * 125 + k0]     : 0.f;
            float v1 = (n < NB && k0 + 1 < 125) ? kern[n * 125 + k0 + 1] : 0.f;
            u[e2] = f2bf(v0) | (f2bf(v1) << 16);
        }
        union { uint4 u4; short8 s8; } cv;
        cv.u4 = make_uint4(u[0], u[1], u[2], u[3]);
        bt[kk] = cv.s8;
    }

    __syncthreads();

    const int t0w = wid << 8;                    // wave owns t in [256w, 256w+256)
    const int rl  = (n + 2) & 7;                 // A-row i = n : alignment class
    const char* xsb = reinterpret_cast<const char*>(xs);
    // F[u] element index s = t0w + 2 + n + 8g + 16u, LDS elem = 1159*rl + s
    const int LB = 2 * (1159 * rl + 2 + n + 8 * g + t0w);

    short8 F[8];
    #pragma unroll
    for (int u = 0; u < 6; ++u)
        F[u] = *reinterpret_cast<const short8*>(xsb + LB + 32 * u);

    const bool bandok = (n < NB);
    float* obase = out + ((size_t)(b * NB + n) * 64 + c) * T_LEN + t0w + 4 * g;

    #pragma unroll
    for (int m = 0; m < 16; ++m) {               // 16-t tile per iter
        F[(m + 6) & 7] = *reinterpret_cast<const short8*>(xsb + LB + 32 * (m + 6));
        f32x4 acc = {0.f, 0.f, 0.f, 0.f};
        #pragma unroll
        for (int kk = 0; kk < 4; ++kk)
            acc = __builtin_amdgcn_mfma_f32_16x16x32_bf16(F[(m + 2 * kk) & 7], bt[kk], acc, 0, 0, 0);
        const int t4 = t0w + 16 * m + 4 * g;
        if (bandok && t4 + 4 <= T_LEN)
            *reinterpret_cast<f32x4*>(obase + 16 * m) = acc;
    }
}

extern "C" void kernel_launch(void* const* d_in, const int* in_sizes, int n_in,
                              void* d_out, int out_size, void* d_ws, size_t ws_size,
                              hipStream_t stream) {
    const float* x    = (const float*)d_in[0];
    const float* kern = (const float*)d_in[1];
    float* out = (float*)d_out;

    fbank_mfma<<<64 * 64, 256, 0, stream>>>(x, kern, out);
}